// Round 3
// baseline (20.803 us; speedup 1.0000x reference)
//
#include <hip/hip_runtime.h>
#include <hip/hip_bf16.h>
#include <math.h>

// ======================= compile-time Wigner 3j =======================
namespace cw {

struct CD { double re, im; };
constexpr CD cmul(CD a, CD b) { return CD{a.re*b.re - a.im*b.im, a.re*b.im + a.im*b.re}; }
constexpr CD cadd(CD a, CD b) { return CD{a.re + b.re, a.im + b.im}; }

template <int N> struct ArrD { double v[N] {}; };
template <int N> struct ArrC { CD v[N] {}; };

constexpr double csqrt_(double x) {
  if (x <= 0.0) return 0.0;
  double g = x > 1.0 ? x : 1.0;
  for (int i = 0; i < 200; ++i) g = 0.5 * (g + x / g);
  return g;
}

constexpr ArrD<32> make_fact() {
  ArrD<32> f{};
  f.v[0] = 1.0;
  for (int i = 1; i < 32; ++i) f.v[i] = f.v[i - 1] * (double)i;
  return f;
}
constexpr ArrD<32> FACT = make_fact();
static_assert(FACT.v[5] == 120.0, "factorial sanity");

constexpr double su2_cg(int j1, int j2, int j3, int m1, int m2, int m3) {
  if (m3 != m1 + m2) return 0.0;
  int vmin = 0;
  if (-j1 + j2 + m3 > vmin) vmin = -j1 + j2 + m3;
  if (-j1 + m1 > vmin) vmin = -j1 + m1;
  int vmax = j2 + j3 + m1;
  if (j3 - j1 + j2 < vmax) vmax = j3 - j1 + j2;
  if (j3 + m3 < vmax) vmax = j3 + m3;
  const double c = csqrt_((2.0 * j3 + 1.0) * FACT.v[j3 + j1 - j2] * FACT.v[j3 - j1 + j2] *
                          FACT.v[j1 + j2 - j3] * FACT.v[j3 + m3] * FACT.v[j3 - m3] /
                          (FACT.v[j1 + j2 + j3 + 1] * FACT.v[j1 - m1] * FACT.v[j1 + m1] *
                           FACT.v[j2 - m2] * FACT.v[j2 + m2]));
  double s = 0.0;
  for (int v = vmin; v <= vmax; ++v) {
    const double sg = ((v + j2 + m2) % 2 == 0) ? 1.0 : -1.0;
    s += sg * FACT.v[j2 + j3 + m1 - v] * FACT.v[j1 - m1 + v] /
         (FACT.v[v] * FACT.v[j3 - j1 + j2 - v] * FACT.v[j3 + m3 - v] * FACT.v[v + j1 - j2 - m3]);
  }
  return c * s;
}

template <int L> constexpr ArrC<(2 * L + 1) * (2 * L + 1)> real_basis() {
  constexpr int n = 2 * L + 1;
  ArrC<n * n> q{};
  const double s = 1.0 / csqrt_(2.0);
  for (int m = -L; m < 0; ++m) {
    q.v[(L + m) * n + (L - m)] = CD{s, 0.0};
    q.v[(L + m) * n + (L + m)] = CD{0.0, -s};
  }
  q.v[L * n + L] = CD{1.0, 0.0};
  for (int m = 1; m <= L; ++m) {
    const double sg = (m % 2 == 0) ? 1.0 : -1.0;
    q.v[(L + m) * n + (L + m)] = CD{sg * s, 0.0};
    q.v[(L + m) * n + (L - m)] = CD{0.0, sg * s};
  }
  CD ph = CD{1.0, 0.0};
  if (L % 4 == 1) ph = CD{0.0, -1.0};
  if (L % 4 == 2) ph = CD{-1.0, 0.0};
  if (L % 4 == 3) ph = CD{0.0, 1.0};
  for (int i = 0; i < n * n; ++i) q.v[i] = cmul(ph, q.v[i]);
  return q;
}

template <int L1, int L2, int L3>
constexpr ArrD<(2 * L1 + 1) * (2 * L2 + 1) * (2 * L3 + 1)> w3j_real() {
  constexpr int n1 = 2 * L1 + 1, n2 = 2 * L2 + 1, n3 = 2 * L3 + 1;
  const ArrC<n1 * n1> Q1 = real_basis<L1>();
  const ArrC<n2 * n2> Q2 = real_basis<L2>();
  const ArrC<n3 * n3> Q3 = real_basis<L3>();
  ArrC<n1 * n2 * n3> T1{};
  for (int a = 0; a < n1; ++a)
    for (int b = 0; b < n2; ++b) {
      const int m3 = (a - L1) + (b - L2);
      if (m3 < -L3 || m3 > L3) continue;
      const int c = L3 + m3;
      const double cg = su2_cg(L1, L2, L3, a - L1, b - L2, m3);
      if (cg == 0.0) continue;
      for (int k = 0; k < n3; ++k) {
        const CD q = Q3.v[k * n3 + c];
        if (q.re != 0.0 || q.im != 0.0)
          T1.v[(a * n2 + b) * n3 + k] = cadd(T1.v[(a * n2 + b) * n3 + k], CD{q.re * cg, -q.im * cg});
      }
    }
  ArrC<n1 * n2 * n3> T2{};
  for (int a = 0; a < n1; ++a)
    for (int b = 0; b < n2; ++b)
      for (int j = 0; j < n2; ++j) {
        const CD q = Q2.v[b * n2 + j];
        if (q.re == 0.0 && q.im == 0.0) continue;
        for (int k = 0; k < n3; ++k) {
          const CD t = T1.v[(a * n2 + b) * n3 + k];
          if (t.re != 0.0 || t.im != 0.0)
            T2.v[(a * n2 + j) * n3 + k] = cadd(T2.v[(a * n2 + j) * n3 + k], cmul(q, t));
        }
      }
  ArrD<n1 * n2 * n3> O{};
  for (int a = 0; a < n1; ++a)
    for (int i = 0; i < n1; ++i) {
      const CD q = Q1.v[a * n1 + i];
      if (q.re == 0.0 && q.im == 0.0) continue;
      for (int j = 0; j < n2; ++j)
        for (int k = 0; k < n3; ++k) {
          const CD t = T2.v[(a * n2 + j) * n3 + k];
          O.v[(i * n2 + j) * n3 + k] += q.re * t.re - q.im * t.im;
        }
    }
  double nrm2 = 0.0;
  for (int e = 0; e < n1 * n2 * n3; ++e) nrm2 += O.v[e] * O.v[e];
  const double inv = 1.0 / csqrt_(nrm2);
  for (int e = 0; e < n1 * n2 * n3; ++e) O.v[e] *= inv;
  return O;
}

constexpr ArrD<81>  W440 = w3j_real<4, 4, 0>();
constexpr ArrD<405> W442 = w3j_real<4, 4, 2>();
constexpr ArrD<169> W660 = w3j_real<6, 6, 0>();
constexpr ArrD<845> W662 = w3j_real<6, 6, 2>();
constexpr ArrD<585> W462 = w3j_real<4, 6, 2>();
constexpr ArrD<585> W642 = w3j_real<6, 4, 2>();
constexpr ArrD<75>  W221 = w3j_real<2, 2, 1>();

constexpr bool sym642() {
  for (int a = 0; a < 9; ++a)
    for (int b = 0; b < 13; ++b)
      for (int k = 0; k < 5; ++k) {
        const double d = W642.v[(b * 9 + a) * 5 + k] - W462.v[(a * 13 + b) * 5 + k];
        if (d > 1e-9 || d < -1e-9) return false;
      }
  return true;
}
static_assert(sym642(), "W642 != W462^T — basis fold invalid");

} // namespace cw

// ======================= packed f32 helpers (v_pk_* on gfx950) =======================
typedef float v2f __attribute__((ext_vector_type(2)));

__device__ __forceinline__ v2f s2(float x) { return (v2f){x, x}; }
__device__ __forceinline__ v2f fma2(v2f a, v2f b, v2f c) {
#if __has_builtin(__builtin_elementwise_fma)
  return __builtin_elementwise_fma(a, b, c);
#else
  return (v2f){fmaf(a.x, b.x, c.x), fmaf(a.y, b.y, c.y)};
#endif
}
__device__ __forceinline__ v2f max2(v2f a, v2f b) { return (v2f){fmaxf(a.x, b.x), fmaxf(a.y, b.y)}; }
__device__ __forceinline__ v2f min2(v2f a, v2f b) { return (v2f){fminf(a.x, b.x), fminf(a.y, b.y)}; }
__device__ __forceinline__ v2f abs2(v2f a) { return (v2f){fabsf(a.x), fabsf(a.y)}; }
__device__ __forceinline__ v2f rcp2(v2f a) { return (v2f){__builtin_amdgcn_rcpf(a.x), __builtin_amdgcn_rcpf(a.y)}; }
__device__ __forceinline__ v2f sqrt2(v2f a) { return (v2f){sqrtf(a.x), sqrtf(a.y)}; }

// minimax atan2, err ~1e-6 rad; poly part packs to v_pk_fma_f32
__device__ __forceinline__ v2f fatan2v(v2f y, v2f x) {
  const v2f ax = abs2(x), ay = abs2(y);
  const v2f mx = max2(ax, ay), mn = min2(ax, ay);
  const v2f a = mn * rcp2(max2(mx, s2(1e-38f)));
  const v2f s = a * a;
  v2f r = fma2(s, fma2(s, fma2(s, fma2(s, fma2(s, s2(-0.0117212f), s2(0.05265332f)),
                                       s2(-0.11643287f)), s2(0.19354346f)), s2(-0.33262347f)),
               s2(0.99997726f));
  r = r * a;
  r.x = (ay.x > ax.x) ? 1.57079637f - r.x : r.x;
  r.y = (ay.y > ax.y) ? 1.57079637f - r.y : r.y;
  r.x = (x.x < 0.f) ? 3.14159274f - r.x : r.x;
  r.y = (x.y < 0.f) ? 3.14159274f - r.y : r.y;
  r.x = (y.x < 0.f) ? -r.x : r.x;
  r.y = (y.y < 0.f) ? -r.y : r.y;
  return r;
}

// ======================= pre-kernel: weight-only coefficients =======================
__global__ void precoef(const float* __restrict__ w44t, const float* __restrict__ w46t,
                        const float* __restrict__ w64t, const float* __restrict__ w66t,
                        const float* __restrict__ wtt, float* __restrict__ cc) {
  const int t = threadIdx.x;
  if (t >= 168) return;
  const int w = t / 84;
  const int pq = (t % 84) / 28;
  const int uvi = t % 28;
  int U = 0, V = 1, idx = 0;
#pragma unroll
  for (int u = 0; u < 8; ++u)
#pragma unroll
    for (int v = u + 1; v < 8; ++v) {
      if (idx == uvi) { U = u; V = v; }
      ++idx;
    }
  const int p = (pq == 2) ? 1 : 0;
  const int q = (pq == 0) ? 1 : 2;
  auto aw = [&](int pp, int uu) -> float {
    return pp == 0 ? w44t[uu] : (pp == 1 ? (w46t[uu] + w64t[uu]) : w66t[uu]);
  };
  const float Aw = wtt[(U * 8 + V) * 2 + w] - wtt[(V * 8 + U) * 2 + w];
  cc[t] = Aw * (aw(p, U) * aw(q, V) - aw(p, V) * aw(q, U));
}

// ======================= main kernel: 2 batch elements / thread, packed f32 =======================
__global__ __launch_bounds__(256) void geo_euler(
    const float* __restrict__ feat,
    const float* __restrict__ w44s2, const float* __restrict__ w66s2,
    const float* __restrict__ cc,
    float* __restrict__ out, int B)
{
  const int t = blockIdx.x * 256 + threadIdx.x;
  const int half = B >> 1; // B is even (262144)
  if (t >= half) return;
  const int b0 = 2 * t;

  // load two rows of 22 floats, interleave into v2f lanes {elem0, elem1}
  v2f f[22];
  {
    const float2* r0 = reinterpret_cast<const float2*>(feat + (size_t)b0 * 22);
    const float2* r1 = reinterpret_cast<const float2*>(feat + (size_t)b0 * 22 + 22);
#pragma unroll
    for (int i = 0; i < 11; ++i) {
      const float2 a = r0[i], b = r1[i];
      f[2 * i]     = (v2f){a.x, b.x};
      f[2 * i + 1] = (v2f){a.y, b.y};
    }
  }
  const v2f* f4 = f;
  const v2f* f6 = f + 9;

  v2f q44 = s2(0.f), q66 = s2(0.f);
  v2f T0[5], T1[5], T2[5];
#pragma unroll
  for (int K = 0; K < 5; ++K) { T0[K] = s2(0.f); T1[K] = s2(0.f); T2[K] = s2(0.f); }

#pragma unroll
  for (int I = 0; I < 9; ++I)
#pragma unroll
    for (int J = I; J < 9; ++J) {
      const v2f p = f4[I] * f4[J];
      {
        const float c = (I == J) ? (float)cw::W440.v[I * 9 + J]
                                 : (float)(cw::W440.v[I * 9 + J] + cw::W440.v[J * 9 + I]);
        if (c != 0.f) q44 = fma2(s2(c), p, q44);
      }
#pragma unroll
      for (int K = 0; K < 5; ++K) {
        const float c = (I == J) ? (float)cw::W442.v[(I * 9 + J) * 5 + K]
                                 : (float)(cw::W442.v[(I * 9 + J) * 5 + K] + cw::W442.v[(J * 9 + I) * 5 + K]);
        if (c != 0.f) T0[K] = fma2(s2(c), p, T0[K]);
      }
    }

#pragma unroll
  for (int I = 0; I < 13; ++I)
#pragma unroll
    for (int J = I; J < 13; ++J) {
      const v2f p = f6[I] * f6[J];
      {
        const float c = (I == J) ? (float)cw::W660.v[I * 13 + J]
                                 : (float)(cw::W660.v[I * 13 + J] + cw::W660.v[J * 13 + I]);
        if (c != 0.f) q66 = fma2(s2(c), p, q66);
      }
#pragma unroll
      for (int K = 0; K < 5; ++K) {
        const float c = (I == J) ? (float)cw::W662.v[(I * 13 + J) * 5 + K]
                                 : (float)(cw::W662.v[(I * 13 + J) * 5 + K] + cw::W662.v[(J * 13 + I) * 5 + K]);
        if (c != 0.f) T2[K] = fma2(s2(c), p, T2[K]);
      }
    }

#pragma unroll
  for (int a = 0; a < 9; ++a)
#pragma unroll
    for (int bb = 0; bb < 13; ++bb) {
      const v2f p = f4[a] * f6[bb];
#pragma unroll
      for (int K = 0; K < 5; ++K) {
        const float c46 = (float)cw::W462.v[(a * 13 + bb) * 5 + K];
        if (c46 != 0.f) T1[K] = fma2(s2(c46), p, T1[K]);
      }
    }

  // gates g_u = sigmoid(C0 * (w44s2[8+u] q44 + w66s2[8+u] q66))
  v2f g[8];
#pragma unroll
  for (int u = 0; u < 8; ++u) {
    const v2f sa = s2(0.70710678118654752f) * fma2(s2(w44s2[8 + u]), q44, s2(w66s2[8 + u]) * q66);
    g[u].x = __builtin_amdgcn_rcpf(1.f + __expf(-sa.x));
    g[u].y = __builtin_amdgcn_rcpf(1.f + __expf(-sa.y));
  }

  // S_w(pq) = sum_{u<v} cc[w][pq][uv] * g_u g_v  (cc uniform -> s_loads)
  v2f S00 = s2(0.f), S01 = s2(0.f), S02 = s2(0.f), S10 = s2(0.f), S11 = s2(0.f), S12 = s2(0.f);
  {
    int idx = 0;
#pragma unroll
    for (int u = 0; u < 8; ++u)
#pragma unroll
      for (int v = u + 1; v < 8; ++v) {
        const v2f Gp = g[u] * g[v];
        S00 = fma2(s2(cc[idx]),        Gp, S00);
        S01 = fma2(s2(cc[28 + idx]),   Gp, S01);
        S02 = fma2(s2(cc[56 + idx]),   Gp, S02);
        S10 = fma2(s2(cc[84 + idx]),   Gp, S10);
        S11 = fma2(s2(cc[112 + idx]),  Gp, S11);
        S12 = fma2(s2(cc[140 + idx]),  Gp, S12);
        ++idx;
      }
  }

  // B_K(T_p,T_q): av_q = C221_K T_q (sparse), then dots
  v2f av1[3][5], av2[3][5];
#pragma unroll
  for (int K = 0; K < 3; ++K)
#pragma unroll
    for (int I = 0; I < 5; ++I) { av1[K][I] = s2(0.f); av2[K][I] = s2(0.f); }
#pragma unroll
  for (int I = 0; I < 5; ++I)
#pragma unroll
    for (int J = 0; J < 5; ++J)
#pragma unroll
      for (int K = 0; K < 3; ++K) {
        const float c = (float)cw::W221.v[(I * 5 + J) * 3 + K];
        if (c != 0.f) {
          av1[K][I] = fma2(s2(c), T1[J], av1[K][I]);
          av2[K][I] = fma2(s2(c), T2[J], av2[K][I]);
        }
      }
  v2f v0[3], v1[3];
#pragma unroll
  for (int K = 0; K < 3; ++K) {
    v2f M0 = s2(0.f), M1 = s2(0.f), M2 = s2(0.f);
#pragma unroll
    for (int I = 0; I < 5; ++I) {
      M0 = fma2(T0[I], av1[K][I], M0);
      M1 = fma2(T0[I], av2[K][I], M1);
      M2 = fma2(T1[I], av2[K][I], M2);
    }
    v0[K] = fma2(M0, S00, fma2(M1, S01, M2 * S02));
    v1[K] = fma2(M0, S10, fma2(M1, S11, M2 * S12));
  }

  // Gram-Schmidt frame + Euler angles (all packed; selects per-component)
  const v2f n0 = sqrt2(fma2(v0[0], v0[0], fma2(v0[1], v0[1], v0[2] * v0[2])));
  const v2f i0 = rcp2(max2(n0, s2(1e-6f)));
  const v2f z0 = v0[0] * i0, z1 = v0[1] * i0, z2 = v0[2] * i0;
  const v2f dot = fma2(z0, v1[0], fma2(z1, v1[1], z2 * v1[2]));
  const v2f xv0 = v1[0] - dot * z0, xv1 = v1[1] - dot * z1, xv2 = v1[2] - dot * z2;
  const v2f nx = sqrt2(fma2(xv0, xv0, fma2(xv1, xv1, xv2 * xv2)));
  const v2f ix = rcp2(max2(nx, s2(1e-6f)));
  const v2f x0 = xv0 * ix, x1 = xv1 * ix, x2 = xv2 * ix;
  const v2f y0 = z1 * x2 - z2 * x1;
  const v2f y1 = z2 * x0 - z0 * x2;
  const v2f y2 = z0 * x1 - z1 * x0;

  const v2f r22 = min2(max2(z2, s2(-1.f)), s2(1.f));
  const v2f sb = sqrt2(max2(s2(1.f) - r22 * r22, s2(0.f)));
  const v2f beta = fatan2v(sb, r22);
  v2f alpha = fatan2v(z1, z0);
  const v2f gs = fatan2v(y2, -x2);
  const v2f gu = fatan2v(-y0, y1);
  v2f gamma;
  const bool safex = sb.x > 1e-6f, safey = sb.y > 1e-6f;
  alpha.x = safex ? alpha.x : 0.f;
  alpha.y = safey ? alpha.y : 0.f;
  gamma.x = safex ? gs.x : gu.x;
  gamma.y = safey ? gs.y : gu.y;

  // stores: angles as float2 pairs, R as 9 float2 (18 contiguous floats)
  reinterpret_cast<float2*>(out)[t]                    = make_float2(alpha.x, alpha.y);
  reinterpret_cast<float2*>(out + B)[t]                = make_float2(beta.x, beta.y);
  reinterpret_cast<float2*>(out + 2 * (size_t)B)[t]    = make_float2(gamma.x, gamma.y);
  float2* Ro = reinterpret_cast<float2*>(out + 3 * (size_t)B + (size_t)b0 * 9);
  Ro[0] = make_float2(x0.x, y0.x);
  Ro[1] = make_float2(z0.x, x1.x);
  Ro[2] = make_float2(y1.x, z1.x);
  Ro[3] = make_float2(x2.x, y2.x);
  Ro[4] = make_float2(z2.x, x0.y);
  Ro[5] = make_float2(y0.y, z0.y);
  Ro[6] = make_float2(x1.y, y1.y);
  Ro[7] = make_float2(z1.y, x2.y);
  Ro[8] = make_float2(y2.y, z2.y);
}

extern "C" void kernel_launch(void* const* d_in, const int* in_sizes, int n_in,
                              void* d_out, int out_size, void* d_ws, size_t ws_size,
                              hipStream_t stream) {
  (void)n_in; (void)out_size; (void)ws_size;
  const float* feat  = (const float*)d_in[0];
  const float* w44s2 = (const float*)d_in[3];
  const float* w66s2 = (const float*)d_in[4];
  const float* w44t  = (const float*)d_in[7];
  const float* w46t  = (const float*)d_in[8];
  const float* w64t  = (const float*)d_in[9];
  const float* w66t  = (const float*)d_in[10];
  const float* wtt   = (const float*)d_in[16];
  float* out = (float*)d_out;
  float* cc = (float*)d_ws; // 168 floats of weight-only coefficients
  const int B = in_sizes[0] / 22;
  const int half = B >> 1;
  precoef<<<1, 256, 0, stream>>>(w44t, w46t, w64t, w66t, wtt, cc);
  geo_euler<<<(half + 255) / 256, 256, 0, stream>>>(feat, w44s2, w66s2, cc, out, B);
}